// Round 14
// baseline (215.049 us; speedup 1.0000x reference)
//
#include <hip/hip_runtime.h>

#define AS1 __attribute__((address_space(1)))
#define AS3 __attribute__((address_space(3)))

typedef short short8 __attribute__((ext_vector_type(8)));
typedef float f32x4 __attribute__((ext_vector_type(4)));

#define DM 1024
#define NH 16
#define DKH 64
#define SEQ 2048
#define NB 4
#define ROWS (NB*SEQ)
#define QTILES (SEQ/128)

__device__ __forceinline__ unsigned short f2bf(float x) {
    union { float f; unsigned u; } v; v.f = x;
    unsigned r = v.u + 0x7fffu + ((v.u >> 16) & 1u);
    return (unsigned short)(r >> 16);
}
__device__ __forceinline__ float bf2f(unsigned short b) {
    union { unsigned u; float f; } v; v.u = ((unsigned)b) << 16;
    return v.f;
}
__device__ __forceinline__ unsigned cvtpk_bf16(float lo, float hi) {
    unsigned r;
    asm("v_cvt_pk_bf16_f32 %0, %1, %2" : "=v"(r) : "v"(lo), "v"(hi));
    return r;
}

__device__ __forceinline__ void gload_lds16(const void* g, void* l) {
    const AS1 unsigned int* gp = (const AS1 unsigned int*)(unsigned long long)g;
    AS3 unsigned int* lp = (AS3 unsigned int*)(unsigned)(unsigned long long)l;
    __builtin_amdgcn_global_load_lds(gp, lp, 16, 0, 0);
}

__device__ __forceinline__ f32x4 mfma_bf16(short8 a, short8 b, f32x4 c) {
    return __builtin_amdgcn_mfma_f32_16x16x32_bf16(a, b, c, 0, 0, 0);
}

// ---------------- fused prep: casts (x, 4 weights) + RoPE table ----------------
__global__ void __launch_bounds__(256) prep_kernel(
    const float* __restrict__ x,
    const float* __restrict__ Wq, const float* __restrict__ Wk,
    const float* __restrict__ Wv, const float* __restrict__ Wo,
    unsigned short* __restrict__ xb, unsigned short* __restrict__ wbase,
    float2* __restrict__ tab) {
    int bid = blockIdx.x, tid = threadIdx.x;
    if (bid < 12288) {
        const float* src;
        unsigned short* dst;
        int i;
        if (bid < 8192) {
            src = x; dst = xb; i = bid * 256 + tid;
        } else {
            int id2 = bid - 8192;
            int w = id2 >> 10;
            src = w == 0 ? Wq : (w == 1 ? Wk : (w == 2 ? Wv : Wo));
            dst = wbase + (size_t)w * (1024 * 1024);
            i = (id2 & 1023) * 256 + tid;
        }
        float4 v = reinterpret_cast<const float4*>(src)[i];
        ushort4 o;
        o.x = f2bf(v.x); o.y = f2bf(v.y); o.z = f2bf(v.z); o.w = f2bf(v.w);
        reinterpret_cast<ushort4*>(dst)[i] = o;
    } else {
        int idx = (bid - 12288) * 256 + tid;
        int pos = idx >> 5, i = idx & 31;
        float inv = powf(10000.0f, -(float)i * (1.0f / 32.0f));
        float ang = (float)pos * inv;
        float2 cs; cs.x = cosf(ang); cs.y = sinf(ang);
        tab[idx] = cs;
    }
}

// ---------------- GEMM C[M,N] = A[M,K] @ B[N,K]^T ----------------
// m97-verified single-buffer schedule: sync; STAGE (global_load_lds); sync; compute.
// outmode 0: bf16 store (+RoPE if rs>0, rs=1.0 -> exact rotation); outmode 2: fused Vt store.
template <int STORE_F32>
__device__ __forceinline__ void gemm_bt_body(const unsigned short* __restrict__ A,
                                             const unsigned short* __restrict__ Bw,
                                             void* __restrict__ C, int m0, int n0,
                                             const float2* __restrict__ tab, float rs,
                                             unsigned short* __restrict__ vt, int outmode) {
    __shared__ unsigned short S[128 * 128];     // As | Bs during K-loop; C-tile in epilogue
    unsigned short* As = S;
    unsigned short* Bs = S + 128 * 64;
    const int tid = threadIdx.x;
    const int lane = tid & 63;
    const int wave = tid >> 6;
    const int wr = wave >> 1, wc = wave & 1;
    const int l15 = lane & 15, l4 = lane >> 4;

    f32x4 acc[4][4];
    #pragma unroll
    for (int m = 0; m < 4; ++m)
        #pragma unroll
        for (int n = 0; n < 4; ++n) { f32x4 z = {0.f, 0.f, 0.f, 0.f}; acc[m][n] = z; }

    const int srow = wave * 8 + (lane >> 3);
    const int gsw = (lane & 7) ^ (srow & 7);
    const unsigned short* Ag = A + (size_t)m0 * DM;
    const unsigned short* Bg = Bw + (size_t)n0 * DM;

    for (int kt = 0; kt < DM; kt += 64) {
        __syncthreads();
        #pragma unroll
        for (int it = 0; it < 4; ++it) {
            int row = it * 32 + srow;
            gload_lds16(Ag + (size_t)row * DM + kt + gsw * 8, (char*)As + (it * 4 + wave) * 1024);
            gload_lds16(Bg + (size_t)row * DM + kt + gsw * 8, (char*)Bs + (it * 4 + wave) * 1024);
        }
        __syncthreads();
        #pragma unroll
        for (int kc = 0; kc < 2; ++kc) {
            short8 af[4], bfr[4];
            #pragma unroll
            for (int m = 0; m < 4; ++m) {
                int row = 64 * wr + 16 * m + l15;
                int off = row * 128 + (((4 * kc + l4) ^ (row & 7)) << 4);
                af[m] = *(const short8*)((const char*)As + off);
            }
            #pragma unroll
            for (int n = 0; n < 4; ++n) {
                int row = 64 * wc + 16 * n + l15;
                int off = row * 128 + (((4 * kc + l4) ^ (row & 7)) << 4);
                bfr[n] = *(const short8*)((const char*)Bs + off);
            }
            #pragma unroll
            for (int m = 0; m < 4; ++m)
                #pragma unroll
                for (int n = 0; n < 4; ++n)
                    acc[m][n] = mfma_bf16(af[m], bfr[n], acc[m][n]);
        }
    }

    if (STORE_F32) {
        int rbase = m0 + 64 * wr + 4 * l4;
        int cbase = n0 + 64 * wc + l15;
        #pragma unroll
        for (int m = 0; m < 4; ++m)
            #pragma unroll
            for (int n = 0; n < 4; ++n) {
                int c = cbase + 16 * n;
                #pragma unroll
                for (int j = 0; j < 4; ++j)
                    ((float*)C)[(size_t)(rbase + 16 * m + j) * DM + c] = acc[m][n][j];
            }
    } else {
        // stage C-tile in LDS with octet swizzle c ^= ((r>>2)&7)<<3
        __syncthreads();
        #pragma unroll
        for (int m = 0; m < 4; ++m) {
            int rb = 64 * wr + 16 * m + 4 * l4;
            int xr = ((rb >> 2) & 7) << 3;
            #pragma unroll
            for (int n = 0; n < 4; ++n) {
                int c = (64 * wc + 16 * n + l15) ^ xr;
                #pragma unroll
                for (int j = 0; j < 4; ++j)
                    S[(rb + j) * 128 + c] = f2bf(acc[m][n][j]);
            }
        }
        __syncthreads();
        if (outmode == 2) {
            // fused V-transpose: tile = tokens m0..m0+127 (one b), features n0..n0+127
            int bidx = m0 >> 11;
            int stile = m0 & (SEQ - 1);
            int hA = n0 >> 6;
            unsigned short* vtb = vt + (size_t)(bidx * (NH * 64) + hA * 64) * SEQ;
            #pragma unroll
            for (int rep = 0; rep < 8; ++rep) {
                int idx = rep * 256 + tid;
                int vtrow = idx >> 4;
                int grp = idx & 15;
                int tg = grp >> 3, kg = grp & 7;
                int kc = kg >> 2, mq = kg & 3;
                short8 o;
                #pragma unroll
                for (int jj = 0; jj < 8; ++jj) {
                    int t = 32 * kc + 16 * (jj >> 2) + 4 * mq + (jj & 3);  // sigma^-1
                    int r = tg * 64 + t;
                    o[jj] = (short)S[r * 128 + (vtrow ^ (((r >> 2) & 7) << 3))];
                }
                *(short8*)(vtb + (size_t)vtrow * SEQ + stile + tg * 64 + kg * 8) = o;
            }
        } else {
            unsigned short* Cg = (unsigned short*)C + (size_t)m0 * DM + n0;
            #pragma unroll
            for (int r8 = 0; r8 < 8; ++r8) {
                int row = r8 * 16 + (tid >> 4);
                int oc = tid & 15;
                short8 v = *(const short8*)(S + row * 128 + ((oc ^ ((row >> 2) & 7)) << 3));
                if (rs > 0.f) {
                    int pos = (m0 + row) & (SEQ - 1);
                    const float2* tp = tab + pos * 32 + (oc & 7) * 4;
                    short8 o;
                    #pragma unroll
                    for (int tt = 0; tt < 4; ++tt) {
                        float cc = tp[tt].x * rs, ss = tp[tt].y * rs;   // rs = 1.0 exact
                        float e0 = bf2f((unsigned short)v[2 * tt]);
                        float e1 = bf2f((unsigned short)v[2 * tt + 1]);
                        o[2 * tt]     = (short)f2bf(e0 * cc - e1 * ss);
                        o[2 * tt + 1] = (short)f2bf(e0 * ss + e1 * cc);
                    }
                    v = o;
                }
                *(short8*)(Cg + (size_t)row * DM + oc * 8) = v;
            }
        }
    }
}

__global__ void __launch_bounds__(256) gemm_qkv_kernel(
    const unsigned short* __restrict__ X,
    const unsigned short* __restrict__ Wq, const unsigned short* __restrict__ Wk,
    const unsigned short* __restrict__ Wv,
    unsigned short* __restrict__ Qo, unsigned short* __restrict__ Ko,
    unsigned short* __restrict__ Vtg,
    const float2* __restrict__ tab) {
    int mt = blockIdx.x >> 3, nt = blockIdx.x & 7;
    int z = blockIdx.z;
    const unsigned short* W = z == 0 ? Wq : (z == 1 ? Wk : Wv);
    unsigned short* O = z == 0 ? Qo : Ko;          // unused for z==2
    gemm_bt_body<0>(X, W, O, mt * 128, nt * 128, tab,
                    z < 2 ? 1.0f : 0.f, Vtg, z == 2 ? 2 : 0);
}

__global__ void __launch_bounds__(256) gemm_out_kernel(
    const unsigned short* __restrict__ AO, const unsigned short* __restrict__ Wo,
    float* __restrict__ out) {
    int mt = blockIdx.x >> 3, nt = blockIdx.x & 7;
    gemm_bt_body<1>(AO, Wo, out, mt * 128, nt * 128, nullptr, 0.f, nullptr, 0);
}

// ---------------- causal flash attention, bf16, D=64 ----------------
// 128 q/block, 4 waves x 2 Q-frags, swapped QK^T.
// R5-verified online-max softmax (mrow/alpha, CS in-kernel, exp2 domain).
// Reg-staged KV: next tile -> private regs during compute; ds_write between two
// __syncthreads. No raw barriers, no waitcnt asm -> race-free by construction.
template <int MODE>
__device__ __forceinline__ void attn_tile(const unsigned short* bufKV,
                                          const short8 (&aq)[2][2], f32x4 (&oacc)[2][4],
                                          float (&mrow)[2], float (&lrow)[2],
                                          int l15, int l4, int qloc) {
    const float CS = 0.125f * 1.44269504088896f;   // scale * log2(e)
    const char* bK = (const char*)bufKV;
    const char* bV = (const char*)bufKV + 8192;
    f32x4 sac[2][4];
    #pragma unroll
    for (int f = 0; f < 2; ++f)
        #pragma unroll
        for (int n = 0; n < 4; ++n) { f32x4 z = {0.f, 0.f, 0.f, 0.f}; sac[f][n] = z; }

    // S^T = K * Q
    #pragma unroll
    for (int kc = 0; kc < 2; ++kc)
        #pragma unroll
        for (int n = 0; n < 4; ++n) {
            int row = 16 * n + l15;
            short8 ak = *(const short8*)(bK + row * 128 + (((4 * kc + l4) ^ (row & 7)) << 4));
            if (MODE < 2) sac[0][n] = mfma_bf16(ak, aq[0][kc], sac[0][n]);
            sac[1][n] = mfma_bf16(ak, aq[1][kc], sac[1][n]);
        }

    short8 pb[2][2];
    #pragma unroll
    for (int f = (MODE == 2 ? 1 : 0); f < 2; ++f) {
        const bool dg = (MODE == 1 && f == 0) || (MODE == 2);
        float sv[4][4];
        float tm = -1e30f;
        #pragma unroll
        for (int n = 0; n < 4; ++n)
            #pragma unroll
            for (int j = 0; j < 4; ++j) {
                float s = sac[f][n][j] * CS;
                if (dg && (16 * n + 4 * l4 + j) > qloc) s = -1e30f;
                sv[n][j] = s;
                tm = fmaxf(tm, s);
            }
        tm = fmaxf(tm, __shfl_xor(tm, 16, 64));
        tm = fmaxf(tm, __shfl_xor(tm, 32, 64));
        float nm = fmaxf(mrow[f], tm);
        float al = exp2f(mrow[f] - nm);
        mrow[f] = nm;
        float pj[4][4];
        float sum = 0.f;
        #pragma unroll
        for (int n = 0; n < 4; ++n)
            #pragma unroll
            for (int j = 0; j < 4; ++j) {
                float p = exp2f(sv[n][j] - nm);
                pj[n][j] = p; sum += p;
            }
        sum += __shfl_xor(sum, 16, 64);
        sum += __shfl_xor(sum, 32, 64);
        lrow[f] = lrow[f] * al + sum;
        #pragma unroll
        for (int n = 0; n < 4; ++n) oacc[f][n] *= al;
        #pragma unroll
        for (int kc = 0; kc < 2; ++kc) {
            union { unsigned u[4]; short8 s8; } P;
            P.u[0] = cvtpk_bf16(pj[2 * kc][0], pj[2 * kc][1]);
            P.u[1] = cvtpk_bf16(pj[2 * kc][2], pj[2 * kc][3]);
            P.u[2] = cvtpk_bf16(pj[2 * kc + 1][0], pj[2 * kc + 1][1]);
            P.u[3] = cvtpk_bf16(pj[2 * kc + 1][2], pj[2 * kc + 1][3]);
            pb[f][kc] = P.s8;
        }
    }

    // O^T += V^T * P^T  (k-slot permutation baked into Vt's global layout)
    #pragma unroll
    for (int kc = 0; kc < 2; ++kc)
        #pragma unroll
        for (int n = 0; n < 4; ++n) {
            int row = 16 * n + l15;
            short8 av = *(const short8*)(bV + row * 128 + (((4 * kc + l4) ^ (row & 7)) << 4));
            if (MODE < 2) oacc[0][n] = mfma_bf16(av, pb[0][kc], oacc[0][n]);
            oacc[1][n] = mfma_bf16(av, pb[1][kc], oacc[1][n]);
        }
}

__global__ void __launch_bounds__(256) attn_kernel(const unsigned short* __restrict__ Q,
                                                   const unsigned short* __restrict__ K,
                                                   const unsigned short* __restrict__ Vtg,
                                                   unsigned short* __restrict__ O) {
    __shared__ unsigned short smem[9216];    // KV buf 16KB | ep overlays (18KB total)

    const int tid = threadIdx.x, lane = tid & 63, wave = tid >> 6;
    const int l15 = lane & 15, l4 = lane >> 4;
    const int bh = blockIdx.x;
    // balanced heavy-first map: stride-4 quads of y sum to equal work
    const int yg = blockIdx.y >> 2, yl = blockIdx.y & 3;
    const int qt = yg == 0 ? 15 - yl : (yg == 1 ? yl : (yg == 2 ? 11 - yl : 4 + yl));
    const int b = bh >> 4, h = bh & 15;
    const size_t base = (size_t)b * SEQ * DM + (size_t)h * DKH;
    const unsigned short* Qb = Q + base;
    const unsigned short* Kb = K + base;
    const unsigned short* Vg = Vtg + (size_t)bh * 64 * SEQ;
    unsigned short* Ob = O + base;

    const int q0 = qt * 128;
    const int qloc = 16 * wave + l15;
    const int NT = 2 * qt + 2;

    short8 aq[2][2];
    #pragma unroll
    for (int f = 0; f < 2; ++f) {
        const unsigned short* p = Qb + (size_t)(q0 + 64 * f + 16 * wave + l15) * DM + 8 * l4;
        aq[f][0] = *(const short8*)p;
        aq[f][1] = *(const short8*)(p + 32);
    }

    f32x4 oacc[2][4];
    #pragma unroll
    for (int f = 0; f < 2; ++f)
        #pragma unroll
        for (int n = 0; n < 4; ++n) { f32x4 z = {0.f, 0.f, 0.f, 0.f}; oacc[f][n] = z; }
    float mrow[2] = {-1e30f, -1e30f};
    float lrow[2] = {0.f, 0.f};

    const int srow = wave * 8 + (lane >> 3);
    const int gsw = (lane & 7) ^ (srow & 7);
    const unsigned short* kp = Kb + (size_t)srow * DM + gsw * 8;
    const unsigned short* vp = Vg + (size_t)srow * SEQ + gsw * 8;
    // this thread's 4 LDS slots (shorts): K it=0/1, V it=0/1
    unsigned short* s0 = smem + ((0 * 4 + wave) * 1024 + lane * 16) / 2;
    unsigned short* s1 = smem + ((1 * 4 + wave) * 1024 + lane * 16) / 2;
    unsigned short* s2 = smem + (8192 + (0 * 4 + wave) * 1024 + lane * 16) / 2;
    unsigned short* s3 = smem + (8192 + (1 * 4 + wave) * 1024 + lane * 16) / 2;

    // prologue: tile 0 -> regs -> LDS
    short8 rk0 = *(const short8*)(kp);
    short8 rk1 = *(const short8*)(kp + 32 * DM);
    short8 rv0 = *(const short8*)(vp);
    short8 rv1 = *(const short8*)(vp + 32 * SEQ);
    kp += 64 * DM; vp += 64;
    *(short8*)s0 = rk0; *(short8*)s1 = rk1;
    *(short8*)s2 = rv0; *(short8*)s3 = rv1;
    __syncthreads();

    for (int t = 0; t < NT; ++t) {
        if (t + 1 < NT) {    // issue next-tile loads into private regs (overlaps compute)
            rk0 = *(const short8*)(kp);
            rk1 = *(const short8*)(kp + 32 * DM);
            rv0 = *(const short8*)(vp);
            rv1 = *(const short8*)(vp + 32 * SEQ);
            kp += 64 * DM; vp += 64;
        }
        if (t < NT - 2)       attn_tile<0>(smem, aq, oacc, mrow, lrow, l15, l4, qloc);
        else if (t == NT - 2) attn_tile<1>(smem, aq, oacc, mrow, lrow, l15, l4, qloc);
        else                  attn_tile<2>(smem, aq, oacc, mrow, lrow, l15, l4, qloc);
        __syncthreads();     // all reads of buf done
        if (t + 1 < NT) {
            *(short8*)s0 = rk0; *(short8*)s1 = rk1;
            *(short8*)s2 = rv0; *(short8*)s3 = rv1;
            __syncthreads(); // buf ready for next tile
        }
    }

    // epilogue: acc (col=q=l15, row=d=16n+4*l4+j) -> LDS -> coalesced store
    unsigned short* ep = smem + wave * 2304;   // 32 rows x 72, per-wave region
    float inv[2] = {1.f / lrow[0], 1.f / lrow[1]};
    #pragma unroll
    for (int f = 0; f < 2; ++f)
        #pragma unroll
        for (int n = 0; n < 4; ++n)
            #pragma unroll
            for (int j = 0; j < 4; ++j)
                ep[(f * 16 + l15) * 72 + 16 * n + 4 * l4 + j] = f2bf(oacc[f][n][j] * inv[f]);
    __syncthreads();
    #pragma unroll
    for (int i = 0; i < 4; ++i) {
        int r = i * 8 + (lane >> 3), cg = lane & 7;
        int grow = q0 + 64 * (r >> 4) + 16 * wave + (r & 15);
        *(short8*)(Ob + (size_t)grow * DM + cg * 8) = *(const short8*)(ep + r * 72 + cg * 8);
    }
}

extern "C" void kernel_launch(void* const* d_in, const int* in_sizes, int n_in,
                              void* d_out, int out_size, void* d_ws, size_t ws_size,
                              hipStream_t stream) {
    (void)in_sizes; (void)n_in; (void)out_size; (void)ws_size;
    const float* x  = (const float*)d_in[0];
    const float* Wq = (const float*)d_in[1];
    const float* Wk = (const float*)d_in[2];
    const float* Wv = (const float*)d_in[3];
    const float* Wo = (const float*)d_in[4];
    float* out = (float*)d_out;

    char* ws = (char*)d_ws;
    const size_t MB = 1024 * 1024;
    unsigned short* xb  = (unsigned short*)(ws);
    unsigned short* wqb = (unsigned short*)(ws + 16 * MB); // wqb..wob contiguous 2MB regions
    unsigned short* wkb = (unsigned short*)(ws + 18 * MB);
    unsigned short* wvb = (unsigned short*)(ws + 20 * MB);
    unsigned short* wob = (unsigned short*)(ws + 22 * MB);
    unsigned short* Qb  = (unsigned short*)(ws + 24 * MB);
    unsigned short* Kb  = (unsigned short*)(ws + 40 * MB);
    unsigned short* Vtg = (unsigned short*)(ws + 56 * MB); // V^T (permuted), written by gemm_qkv
    unsigned short* AO  = (unsigned short*)(ws + 72 * MB);
    float2* tab = (float2*)(ws + 88 * MB);

    prep_kernel<<<12544, 256, 0, stream>>>(x, Wq, Wk, Wv, Wo, xb, wqb, tab);
    gemm_qkv_kernel<<<dim3(512, 1, 3), 256, 0, stream>>>(xb, wqb, wkb, wvb, Qb, Kb, Vtg, tab);
    attn_kernel<<<dim3(NB * NH, QTILES), 256, 0, stream>>>(Qb, Kb, Vtg, AO);
    gemm_out_kernel<<<512, 256, 0, stream>>>(AO, wob, out);
}

// Round 15
// 204.085 us; speedup vs baseline: 1.0537x; 1.0537x over previous
//
#include <hip/hip_runtime.h>

#define AS1 __attribute__((address_space(1)))
#define AS3 __attribute__((address_space(3)))

typedef short short8 __attribute__((ext_vector_type(8)));
typedef float f32x4 __attribute__((ext_vector_type(4)));

#define DM 1024
#define NH 16
#define DKH 64
#define SEQ 2048
#define NB 4
#define ROWS (NB*SEQ)
#define QTILES (SEQ/128)

__device__ __forceinline__ unsigned short f2bf(float x) {
    union { float f; unsigned u; } v; v.f = x;
    unsigned r = v.u + 0x7fffu + ((v.u >> 16) & 1u);
    return (unsigned short)(r >> 16);
}
__device__ __forceinline__ float bf2f(unsigned short b) {
    union { unsigned u; float f; } v; v.u = ((unsigned)b) << 16;
    return v.f;
}
__device__ __forceinline__ unsigned cvtpk_bf16(float lo, float hi) {
    unsigned r;
    asm("v_cvt_pk_bf16_f32 %0, %1, %2" : "=v"(r) : "v"(lo), "v"(hi));
    return r;
}

__device__ __forceinline__ void gload_lds16(const void* g, void* l) {
    const AS1 unsigned int* gp = (const AS1 unsigned int*)(unsigned long long)g;
    AS3 unsigned int* lp = (AS3 unsigned int*)(unsigned)(unsigned long long)l;
    __builtin_amdgcn_global_load_lds(gp, lp, 16, 0, 0);
}

__device__ __forceinline__ f32x4 mfma_bf16(short8 a, short8 b, f32x4 c) {
    return __builtin_amdgcn_mfma_f32_16x16x32_bf16(a, b, c, 0, 0, 0);
}

// ---------------- fused prep: casts (x, 4 weights) + RoPE table ----------------
__global__ void __launch_bounds__(256) prep_kernel(
    const float* __restrict__ x,
    const float* __restrict__ Wq, const float* __restrict__ Wk,
    const float* __restrict__ Wv, const float* __restrict__ Wo,
    unsigned short* __restrict__ xb, unsigned short* __restrict__ wbase,
    float2* __restrict__ tab) {
    int bid = blockIdx.x, tid = threadIdx.x;
    if (bid < 12288) {
        const float* src;
        unsigned short* dst;
        int i;
        if (bid < 8192) {
            src = x; dst = xb; i = bid * 256 + tid;
        } else {
            int id2 = bid - 8192;
            int w = id2 >> 10;
            src = w == 0 ? Wq : (w == 1 ? Wk : (w == 2 ? Wv : Wo));
            dst = wbase + (size_t)w * (1024 * 1024);
            i = (id2 & 1023) * 256 + tid;
        }
        float4 v = reinterpret_cast<const float4*>(src)[i];
        ushort4 o;
        o.x = f2bf(v.x); o.y = f2bf(v.y); o.z = f2bf(v.z); o.w = f2bf(v.w);
        reinterpret_cast<ushort4*>(dst)[i] = o;
    } else {
        int idx = (bid - 12288) * 256 + tid;
        int pos = idx >> 5, i = idx & 31;
        float inv = powf(10000.0f, -(float)i * (1.0f / 32.0f));
        float ang = (float)pos * inv;
        float2 cs; cs.x = cosf(ang); cs.y = sinf(ang);
        tab[idx] = cs;
    }
}

// ---------------- GEMM C[M,N] = A[M,K] @ B[N,K]^T ----------------
// m97-verified single-buffer schedule: sync; STAGE (global_load_lds); sync; compute.
// outmode 0: bf16 store (+RoPE if rs>0, rs=1.0 -> exact rotation); outmode 2: fused Vt store.
template <int STORE_F32>
__device__ __forceinline__ void gemm_bt_body(const unsigned short* __restrict__ A,
                                             const unsigned short* __restrict__ Bw,
                                             void* __restrict__ C, int m0, int n0,
                                             const float2* __restrict__ tab, float rs,
                                             unsigned short* __restrict__ vt, int outmode) {
    __shared__ unsigned short S[128 * 128];     // As | Bs during K-loop; C-tile in epilogue
    unsigned short* As = S;
    unsigned short* Bs = S + 128 * 64;
    const int tid = threadIdx.x;
    const int lane = tid & 63;
    const int wave = tid >> 6;
    const int wr = wave >> 1, wc = wave & 1;
    const int l15 = lane & 15, l4 = lane >> 4;

    f32x4 acc[4][4];
    #pragma unroll
    for (int m = 0; m < 4; ++m)
        #pragma unroll
        for (int n = 0; n < 4; ++n) { f32x4 z = {0.f, 0.f, 0.f, 0.f}; acc[m][n] = z; }

    const int srow = wave * 8 + (lane >> 3);
    const int gsw = (lane & 7) ^ (srow & 7);
    const unsigned short* Ag = A + (size_t)m0 * DM;
    const unsigned short* Bg = Bw + (size_t)n0 * DM;

    for (int kt = 0; kt < DM; kt += 64) {
        __syncthreads();
        #pragma unroll
        for (int it = 0; it < 4; ++it) {
            int row = it * 32 + srow;
            gload_lds16(Ag + (size_t)row * DM + kt + gsw * 8, (char*)As + (it * 4 + wave) * 1024);
            gload_lds16(Bg + (size_t)row * DM + kt + gsw * 8, (char*)Bs + (it * 4 + wave) * 1024);
        }
        __syncthreads();
        #pragma unroll
        for (int kc = 0; kc < 2; ++kc) {
            short8 af[4], bfr[4];
            #pragma unroll
            for (int m = 0; m < 4; ++m) {
                int row = 64 * wr + 16 * m + l15;
                int off = row * 128 + (((4 * kc + l4) ^ (row & 7)) << 4);
                af[m] = *(const short8*)((const char*)As + off);
            }
            #pragma unroll
            for (int n = 0; n < 4; ++n) {
                int row = 64 * wc + 16 * n + l15;
                int off = row * 128 + (((4 * kc + l4) ^ (row & 7)) << 4);
                bfr[n] = *(const short8*)((const char*)Bs + off);
            }
            #pragma unroll
            for (int m = 0; m < 4; ++m)
                #pragma unroll
                for (int n = 0; n < 4; ++n)
                    acc[m][n] = mfma_bf16(af[m], bfr[n], acc[m][n]);
        }
    }

    if (STORE_F32) {
        int rbase = m0 + 64 * wr + 4 * l4;
        int cbase = n0 + 64 * wc + l15;
        #pragma unroll
        for (int m = 0; m < 4; ++m)
            #pragma unroll
            for (int n = 0; n < 4; ++n) {
                int c = cbase + 16 * n;
                #pragma unroll
                for (int j = 0; j < 4; ++j)
                    ((float*)C)[(size_t)(rbase + 16 * m + j) * DM + c] = acc[m][n][j];
            }
    } else {
        // stage C-tile in LDS with octet swizzle c ^= ((r>>2)&7)<<3
        __syncthreads();
        #pragma unroll
        for (int m = 0; m < 4; ++m) {
            int rb = 64 * wr + 16 * m + 4 * l4;
            int xr = ((rb >> 2) & 7) << 3;
            #pragma unroll
            for (int n = 0; n < 4; ++n) {
                int c = (64 * wc + 16 * n + l15) ^ xr;
                #pragma unroll
                for (int j = 0; j < 4; ++j)
                    S[(rb + j) * 128 + c] = f2bf(acc[m][n][j]);
            }
        }
        __syncthreads();
        if (outmode == 2) {
            // fused V-transpose: tile = tokens m0..m0+127 (one b), features n0..n0+127
            int bidx = m0 >> 11;
            int stile = m0 & (SEQ - 1);
            int hA = n0 >> 6;
            unsigned short* vtb = vt + (size_t)(bidx * (NH * 64) + hA * 64) * SEQ;
            #pragma unroll
            for (int rep = 0; rep < 8; ++rep) {
                int idx = rep * 256 + tid;
                int vtrow = idx >> 4;
                int grp = idx & 15;
                int tg = grp >> 3, kg = grp & 7;
                int kc = kg >> 2, mq = kg & 3;
                short8 o;
                #pragma unroll
                for (int jj = 0; jj < 8; ++jj) {
                    int t = 32 * kc + 16 * (jj >> 2) + 4 * mq + (jj & 3);  // sigma^-1
                    int r = tg * 64 + t;
                    o[jj] = (short)S[r * 128 + (vtrow ^ (((r >> 2) & 7) << 3))];
                }
                *(short8*)(vtb + (size_t)vtrow * SEQ + stile + tg * 64 + kg * 8) = o;
            }
        } else {
            unsigned short* Cg = (unsigned short*)C + (size_t)m0 * DM + n0;
            #pragma unroll
            for (int r8 = 0; r8 < 8; ++r8) {
                int row = r8 * 16 + (tid >> 4);
                int oc = tid & 15;
                short8 v = *(const short8*)(S + row * 128 + ((oc ^ ((row >> 2) & 7)) << 3));
                if (rs > 0.f) {
                    int pos = (m0 + row) & (SEQ - 1);
                    const float2* tp = tab + pos * 32 + (oc & 7) * 4;
                    short8 o;
                    #pragma unroll
                    for (int tt = 0; tt < 4; ++tt) {
                        float cc = tp[tt].x * rs, ss = tp[tt].y * rs;   // rs = 1.0 exact
                        float e0 = bf2f((unsigned short)v[2 * tt]);
                        float e1 = bf2f((unsigned short)v[2 * tt + 1]);
                        o[2 * tt]     = (short)f2bf(e0 * cc - e1 * ss);
                        o[2 * tt + 1] = (short)f2bf(e0 * ss + e1 * cc);
                    }
                    v = o;
                }
                *(short8*)(Cg + (size_t)row * DM + oc * 8) = v;
            }
        }
    }
}

__global__ void __launch_bounds__(256) gemm_qkv_kernel(
    const unsigned short* __restrict__ X,
    const unsigned short* __restrict__ Wq, const unsigned short* __restrict__ Wk,
    const unsigned short* __restrict__ Wv,
    unsigned short* __restrict__ Qo, unsigned short* __restrict__ Ko,
    unsigned short* __restrict__ Vtg,
    const float2* __restrict__ tab) {
    // XCD-chunked bijective swizzle: each XCD gets 8 consecutive mt values (A-panel L2 reuse)
    int o = blockIdx.x;                  // 1536 blocks, 1536 % 8 == 0
    int v = (o & 7) * 192 + (o >> 3);
    int mt = v / 24;
    int c = v - mt * 24;
    int z = c >> 3, nt = c & 7;
    const unsigned short* W = z == 0 ? Wq : (z == 1 ? Wk : Wv);
    unsigned short* O = z == 0 ? Qo : Ko;          // unused for z==2
    gemm_bt_body<0>(X, W, O, mt * 128, nt * 128, tab,
                    z < 2 ? 1.0f : 0.f, Vtg, z == 2 ? 2 : 0);
}

__global__ void __launch_bounds__(256) gemm_out_kernel(
    const unsigned short* __restrict__ AO, const unsigned short* __restrict__ Wo,
    float* __restrict__ out) {
    int o = blockIdx.x;                  // 512 blocks
    int v = (o & 7) * 64 + (o >> 3);
    int mt = v >> 3, nt = v & 7;
    gemm_bt_body<1>(AO, Wo, out, mt * 128, nt * 128, nullptr, 0.f, nullptr, 0);
}

// ---------------- causal flash attention, bf16, D=64 ----------------
// 128 q/block, 4 waves x 2 Q-frags, swapped QK^T.
// R5-verified online-max softmax (mrow/alpha, CS in-kernel, exp2 domain).
// Reg-staged KV with DOUBLE-buffered LDS, ONE __syncthreads per tile:
// iteration t issues next-tile global loads, computes buf[t&1], ds_writes
// buf[(t+1)&1] (prev readers fenced by t-1's sync), then syncs. All ordering
// is compiler-visible (plain LDS stores + __syncthreads) -> race-free.
template <int MODE>
__device__ __forceinline__ void attn_tile(const unsigned short* bufKV,
                                          const short8 (&aq)[2][2], f32x4 (&oacc)[2][4],
                                          float (&mrow)[2], float (&lrow)[2],
                                          int l15, int l4, int qloc) {
    const float CS = 0.125f * 1.44269504088896f;   // scale * log2(e)
    const char* bK = (const char*)bufKV;
    const char* bV = (const char*)bufKV + 8192;
    f32x4 sac[2][4];
    #pragma unroll
    for (int f = 0; f < 2; ++f)
        #pragma unroll
        for (int n = 0; n < 4; ++n) { f32x4 z = {0.f, 0.f, 0.f, 0.f}; sac[f][n] = z; }

    // S^T = K * Q
    #pragma unroll
    for (int kc = 0; kc < 2; ++kc)
        #pragma unroll
        for (int n = 0; n < 4; ++n) {
            int row = 16 * n + l15;
            short8 ak = *(const short8*)(bK + row * 128 + (((4 * kc + l4) ^ (row & 7)) << 4));
            if (MODE < 2) sac[0][n] = mfma_bf16(ak, aq[0][kc], sac[0][n]);
            sac[1][n] = mfma_bf16(ak, aq[1][kc], sac[1][n]);
        }

    short8 pb[2][2];
    #pragma unroll
    for (int f = (MODE == 2 ? 1 : 0); f < 2; ++f) {
        const bool dg = (MODE == 1 && f == 0) || (MODE == 2);
        float sv[4][4];
        float tm = -1e30f;
        #pragma unroll
        for (int n = 0; n < 4; ++n)
            #pragma unroll
            for (int j = 0; j < 4; ++j) {
                float s = sac[f][n][j] * CS;
                if (dg && (16 * n + 4 * l4 + j) > qloc) s = -1e30f;
                sv[n][j] = s;
                tm = fmaxf(tm, s);
            }
        tm = fmaxf(tm, __shfl_xor(tm, 16, 64));
        tm = fmaxf(tm, __shfl_xor(tm, 32, 64));
        float nm = fmaxf(mrow[f], tm);
        float al = exp2f(mrow[f] - nm);
        mrow[f] = nm;
        float pj[4][4];
        float sum = 0.f;
        #pragma unroll
        for (int n = 0; n < 4; ++n)
            #pragma unroll
            for (int j = 0; j < 4; ++j) {
                float p = exp2f(sv[n][j] - nm);
                pj[n][j] = p; sum += p;
            }
        sum += __shfl_xor(sum, 16, 64);
        sum += __shfl_xor(sum, 32, 64);
        lrow[f] = lrow[f] * al + sum;
        #pragma unroll
        for (int n = 0; n < 4; ++n) oacc[f][n] *= al;
        #pragma unroll
        for (int kc = 0; kc < 2; ++kc) {
            union { unsigned u[4]; short8 s8; } P;
            P.u[0] = cvtpk_bf16(pj[2 * kc][0], pj[2 * kc][1]);
            P.u[1] = cvtpk_bf16(pj[2 * kc][2], pj[2 * kc][3]);
            P.u[2] = cvtpk_bf16(pj[2 * kc + 1][0], pj[2 * kc + 1][1]);
            P.u[3] = cvtpk_bf16(pj[2 * kc + 1][2], pj[2 * kc + 1][3]);
            pb[f][kc] = P.s8;
        }
    }

    // O^T += V^T * P^T  (k-slot permutation baked into Vt's global layout)
    #pragma unroll
    for (int kc = 0; kc < 2; ++kc)
        #pragma unroll
        for (int n = 0; n < 4; ++n) {
            int row = 16 * n + l15;
            short8 av = *(const short8*)(bV + row * 128 + (((4 * kc + l4) ^ (row & 7)) << 4));
            if (MODE < 2) oacc[0][n] = mfma_bf16(av, pb[0][kc], oacc[0][n]);
            oacc[1][n] = mfma_bf16(av, pb[1][kc], oacc[1][n]);
        }
}

__global__ void __launch_bounds__(256) attn_kernel(const unsigned short* __restrict__ Q,
                                                   const unsigned short* __restrict__ K,
                                                   const unsigned short* __restrict__ Vtg,
                                                   unsigned short* __restrict__ O) {
    __shared__ unsigned short smem[16384];   // 2 x (K 4096 | V 4096) shorts; ep overlays after final sync

    const int tid = threadIdx.x, lane = tid & 63, wave = tid >> 6;
    const int l15 = lane & 15, l4 = lane >> 4;
    const int bh = blockIdx.x;
    // balanced heavy-first map: stride-4 quads of y sum to equal work
    const int yg = blockIdx.y >> 2, yl = blockIdx.y & 3;
    const int qt = yg == 0 ? 15 - yl : (yg == 1 ? yl : (yg == 2 ? 11 - yl : 4 + yl));
    const int b = bh >> 4, h = bh & 15;
    const size_t base = (size_t)b * SEQ * DM + (size_t)h * DKH;
    const unsigned short* Qb = Q + base;
    const unsigned short* Kb = K + base;
    const unsigned short* Vg = Vtg + (size_t)bh * 64 * SEQ;
    unsigned short* Ob = O + base;

    const int q0 = qt * 128;
    const int qloc = 16 * wave + l15;
    const int NT = 2 * qt + 2;

    short8 aq[2][2];
    #pragma unroll
    for (int f = 0; f < 2; ++f) {
        const unsigned short* p = Qb + (size_t)(q0 + 64 * f + 16 * wave + l15) * DM + 8 * l4;
        aq[f][0] = *(const short8*)p;
        aq[f][1] = *(const short8*)(p + 32);
    }

    f32x4 oacc[2][4];
    #pragma unroll
    for (int f = 0; f < 2; ++f)
        #pragma unroll
        for (int n = 0; n < 4; ++n) { f32x4 z = {0.f, 0.f, 0.f, 0.f}; oacc[f][n] = z; }
    float mrow[2] = {-1e30f, -1e30f};
    float lrow[2] = {0.f, 0.f};

    const int srow = wave * 8 + (lane >> 3);
    const int gsw = (lane & 7) ^ (srow & 7);
    const unsigned short* kp = Kb + (size_t)srow * DM + gsw * 8;
    const unsigned short* vp = Vg + (size_t)srow * SEQ + gsw * 8;
    // this thread's 4 LDS slot offsets within a buffer (in shorts)
    const int c0 = ((0 * 4 + wave) * 1024 + lane * 16) / 2;
    const int c1 = ((1 * 4 + wave) * 1024 + lane * 16) / 2;
    const int c2 = (8192 + (0 * 4 + wave) * 1024 + lane * 16) / 2;
    const int c3 = (8192 + (1 * 4 + wave) * 1024 + lane * 16) / 2;

    // prologue: tile 0 -> regs -> buf0
    short8 rk0 = *(const short8*)(kp);
    short8 rk1 = *(const short8*)(kp + 32 * DM);
    short8 rv0 = *(const short8*)(vp);
    short8 rv1 = *(const short8*)(vp + 32 * SEQ);
    kp += 64 * DM; vp += 64;
    *(short8*)(smem + c0) = rk0; *(short8*)(smem + c1) = rk1;
    *(short8*)(smem + c2) = rv0; *(short8*)(smem + c3) = rv1;
    __syncthreads();

    for (int t = 0; t < NT; ++t) {
        const bool pre = (t + 1 < NT);
        if (pre) {           // issue next-tile loads into private regs (overlaps compute)
            rk0 = *(const short8*)(kp);
            rk1 = *(const short8*)(kp + 32 * DM);
            rv0 = *(const short8*)(vp);
            rv1 = *(const short8*)(vp + 32 * SEQ);
            kp += 64 * DM; vp += 64;
        }
        const unsigned short* buf = smem + (t & 1) * 8192;
        if (t < NT - 2)       attn_tile<0>(buf, aq, oacc, mrow, lrow, l15, l4, qloc);
        else if (t == NT - 2) attn_tile<1>(buf, aq, oacc, mrow, lrow, l15, l4, qloc);
        else                  attn_tile<2>(buf, aq, oacc, mrow, lrow, l15, l4, qloc);
        if (pre) {           // write to the OTHER buffer (its readers fenced at t-1's sync)
            unsigned short* db = smem + ((t + 1) & 1) * 8192;
            *(short8*)(db + c0) = rk0; *(short8*)(db + c1) = rk1;
            *(short8*)(db + c2) = rv0; *(short8*)(db + c3) = rv1;
        }
        __syncthreads();
    }

    // epilogue: acc (col=q=l15, row=d=16n+4*l4+j) -> LDS -> coalesced store
    unsigned short* ep = smem + wave * 2304;   // 32 rows x 72, per-wave region
    float inv[2] = {1.f / lrow[0], 1.f / lrow[1]};
    #pragma unroll
    for (int f = 0; f < 2; ++f)
        #pragma unroll
        for (int n = 0; n < 4; ++n)
            #pragma unroll
            for (int j = 0; j < 4; ++j)
                ep[(f * 16 + l15) * 72 + 16 * n + 4 * l4 + j] = f2bf(oacc[f][n][j] * inv[f]);
    __syncthreads();
    #pragma unroll
    for (int i = 0; i < 4; ++i) {
        int r = i * 8 + (lane >> 3), cg = lane & 7;
        int grow = q0 + 64 * (r >> 4) + 16 * wave + (r & 15);
        *(short8*)(Ob + (size_t)grow * DM + cg * 8) = *(const short8*)(ep + r * 72 + cg * 8);
    }
}

extern "C" void kernel_launch(void* const* d_in, const int* in_sizes, int n_in,
                              void* d_out, int out_size, void* d_ws, size_t ws_size,
                              hipStream_t stream) {
    (void)in_sizes; (void)n_in; (void)out_size; (void)ws_size;
    const float* x  = (const float*)d_in[0];
    const float* Wq = (const float*)d_in[1];
    const float* Wk = (const float*)d_in[2];
    const float* Wv = (const float*)d_in[3];
    const float* Wo = (const float*)d_in[4];
    float* out = (float*)d_out;

    char* ws = (char*)d_ws;
    const size_t MB = 1024 * 1024;
    unsigned short* xb  = (unsigned short*)(ws);
    unsigned short* wqb = (unsigned short*)(ws + 16 * MB); // wqb..wob contiguous 2MB regions
    unsigned short* wkb = (unsigned short*)(ws + 18 * MB);
    unsigned short* wvb = (unsigned short*)(ws + 20 * MB);
    unsigned short* wob = (unsigned short*)(ws + 22 * MB);
    unsigned short* Qb  = (unsigned short*)(ws + 24 * MB);
    unsigned short* Kb  = (unsigned short*)(ws + 40 * MB);
    unsigned short* Vtg = (unsigned short*)(ws + 56 * MB); // V^T (permuted), written by gemm_qkv
    unsigned short* AO  = (unsigned short*)(ws + 72 * MB);
    float2* tab = (float2*)(ws + 88 * MB);

    prep_kernel<<<12544, 256, 0, stream>>>(x, Wq, Wk, Wv, Wo, xb, wqb, tab);
    gemm_qkv_kernel<<<1536, 256, 0, stream>>>(xb, wqb, wkb, wvb, Qb, Kb, Vtg, tab);
    attn_kernel<<<dim3(NB * NH, QTILES), 256, 0, stream>>>(Qb, Kb, Vtg, AO);
    gemm_out_kernel<<<512, 256, 0, stream>>>(AO, wob, out);
}